// Round 1
// baseline (523.148 us; speedup 1.0000x reference)
//
#include <hip/hip_runtime.h>

// Problem constants (match reference)
constexpr int S_ = 200000;   // master nodes
constexpr int N_ = 250000;   // new nodes
// L = B = 64

constexpr int ENC_GRID = 1024;
constexpr int NCHUNK   = (N_ + 63) / 64;   // 3907

// ---------------------------------------------------------------------------
// K1: added[n] = (nn_m[nn_n[n]] != n); c_m histogram (added only, over nn_n);
//     ecnt[j] = #masters with nn_m=j  +  added[j]  (extended segment size).
__global__ void k_added_counts(const int* __restrict__ nn_n, const int* __restrict__ nn_m,
                               int* __restrict__ added, int* __restrict__ c_m,
                               int* __restrict__ ecnt) {
    int i = blockIdx.x * 256 + threadIdx.x;
    if (i < N_) {
        int m = nn_n[i];
        int a = (nn_m[m] != i) ? 1 : 0;
        added[i] = a;
        if (a) {
            atomicAdd(&c_m[m], 1);
            atomicAdd(&ecnt[i], 1);
        }
    }
    if (i < S_) {
        atomicAdd(&ecnt[nn_m[i]], 1);
    }
}

// ---------------------------------------------------------------------------
// K2: per-block sums of ecnt (1024 elements / block) for the exclusive scan.
__global__ void k_scan_blocksum(const int* __restrict__ ecnt, int* __restrict__ bsum) {
    __shared__ int sd[256];
    int b = blockIdx.x, t = threadIdx.x;
    int base = b * 1024 + t * 4;
    int s = 0;
#pragma unroll
    for (int k = 0; k < 4; k++) { int idx = base + k; if (idx < N_) s += ecnt[idx]; }
    sd[t] = s;
    __syncthreads();
    for (int off = 128; off > 0; off >>= 1) {
        if (t < off) sd[t] += sd[t + off];
        __syncthreads();
    }
    if (t == 0) bsum[b] = sd[0];
}

// K3: exclusive scan -> offs.
__global__ void k_scan_apply(const int* __restrict__ ecnt, const int* __restrict__ bsum,
                             int* __restrict__ offs) {
    __shared__ int sd[256];
    __shared__ int sp[256];
    int b = blockIdx.x, t = threadIdx.x;
    sp[t] = (t < b) ? bsum[t] : 0;
    __syncthreads();
    for (int off = 128; off > 0; off >>= 1) {
        if (t < off) sp[t] += sp[t + off];
        __syncthreads();
    }
    int prev = sp[0];

    int base = b * 1024 + t * 4;
    int v[4]; int s = 0;
#pragma unroll
    for (int k = 0; k < 4; k++) { int idx = base + k; v[k] = (idx < N_) ? ecnt[idx] : 0; s += v[k]; }
    sd[t] = s;
    __syncthreads();
    for (int off = 1; off < 256; off <<= 1) {
        int xv = (t >= off) ? sd[t - off] : 0;
        __syncthreads();
        sd[t] += xv;
        __syncthreads();
    }
    int run = prev + sd[t] - s;
#pragma unroll
    for (int k = 0; k < 4; k++) {
        int idx = base + k;
        if (idx < N_) offs[idx] = run;
        run += v[k];
    }
}

// K4: extended CSR fill — masters (nn_m inverse) plus the added contributor
//     nn_n[j] appended to segment j.
__global__ void k_fill(const int* __restrict__ nn_m, const int* __restrict__ nn_n,
                       const int* __restrict__ added, const int* __restrict__ offs,
                       int* __restrict__ fill, int* __restrict__ elist) {
    int i = blockIdx.x * 256 + threadIdx.x;
    if (i < S_) {
        int j = nn_m[i];
        int p = atomicAdd(&fill[j], 1);
        elist[offs[j] + p] = i;
    }
    if (i < N_ && added[i]) {
        int p = atomicAdd(&fill[i], 1);
        elist[offs[i] + p] = nn_n[i];
    }
}

// ---------------------------------------------------------------------------
// K5: We_n[j,:] = sum_{m in elist(j)} We_m[m,:] / (c_m[m]+1).
// One wave serves FOUR segments concurrently (4 gathers in flight -> 4x MLP).
// lane = column; all control flow is wave-uniform.
__global__ __launch_bounds__(256) void k_wen(
        const float* __restrict__ We_m, const int* __restrict__ c_m,
        const int* __restrict__ ecnt, const int* __restrict__ offs,
        const int* __restrict__ elist, float* __restrict__ We_n) {
    int t = threadIdx.x;
    int lane = t & 63;
    int wid = blockIdx.x * 4 + (t >> 6);
    int jb = wid * 4;                     // 4 segments per wave
    if (jb >= N_) return;
    int c[4], o[4];
    float acc[4];
#pragma unroll
    for (int s = 0; s < 4; s++) {
        int j = jb + s;
        bool v = (j < N_);
        c[s] = v ? ecnt[j] : 0;
        o[s] = v ? offs[j] : 0;
        acc[s] = 0.f;
    }
    int cmax = max(max(c[0], c[1]), max(c[2], c[3]));
    for (int q = 0; q < cmax; q++) {
        int mm[4];
#pragma unroll
        for (int s = 0; s < 4; s++)
            mm[s] = (q < c[s]) ? elist[o[s] + q] : -1;   // 4 independent broadcast loads
        float row[4], sc[4];
#pragma unroll
        for (int s = 0; s < 4; s++) {
            if (mm[s] >= 0) {
                row[s] = We_m[(size_t)mm[s] * 64 + lane]; // 4 independent row gathers
                sc[s]  = 1.0f / (float)(c_m[mm[s]] + 1);
            }
        }
#pragma unroll
        for (int s = 0; s < 4; s++)
            if (mm[s] >= 0) acc[s] += row[s] * sc[s];
    }
#pragma unroll
    for (int s = 0; s < 4; s++) {
        int j = jb + s;
        if (j < N_) We_n[(size_t)j * 64 + lane] = acc[s];
    }
}

// ---------------------------------------------------------------------------
// K6: encode GEMM z[b,l] = sum_n x[b,n]*We_n[n,l].
// Rewritten as classic LDS-tiled outer-product GEMM with per-wave K-split:
//   - per 64-chunk: stage xt[k][b] (reg transpose, XOR-swizzled cols) and
//     wt[k][l] (coalesced float4 copy) in LDS
//   - wave w computes k in [w*16, w*16+16) of the chunk over the FULL 64x64
//     output with an 8x8 per-lane register tile: 4 ds_read_b128 per k per
//     wave feed 64 fmacs (VALU-dominant; all LDS reads <=2-way conflicts)
//   - cross-wave combine via LDS reduction, then wave 0 atomically adds the
//     block's 64x64 partial into zp2 (same atomic count as before).
__global__ __launch_bounds__(256, 4) void k_encode(const float* __restrict__ x,
        const float* __restrict__ We_n, float* __restrict__ zp2) {
    __shared__ float xt[64][68];          // x^T tile, swizzled cols, pad 68 (16B-aligned rows)
    __shared__ float wt[64][64];          // We_n tile (natural layout)
    int t = threadIdx.x;
    int lane = t & 63;
    int wv = t >> 6;                       // wave id 0..3
    int lb = lane >> 3;                    // b-block 0..7  -> b = lb*8 + i
    int ll = lane & 7;                     // l-block 0..7  -> l = ll*8 + j
    float acc[64];                         // acc[i*8+j]
#pragma unroll
    for (int i = 0; i < 64; i++) acc[i] = 0.f;

    for (int c = blockIdx.x; c < NCHUNK; c += ENC_GRID) {
        int n0 = c * 64;
        bool full = (n0 + 64 <= N_);
        __syncthreads();                   // previous chunk's reads done
        if (full) {
#pragma unroll
            for (int r = 0; r < 4; r++) {
                int flat = r * 256 + t;
                int b  = flat >> 4;        // 0..63
                int j4 = flat & 15;        // 0..15 (k-quad)
                float4 v = *(const float4*)&x[(size_t)b * N_ + n0 + j4 * 4];
                int bc = b ^ (((j4 ^ (j4 >> 2)) & 7) << 3);
                int k4 = j4 * 4;
                xt[k4 + 0][bc] = v.x;
                xt[k4 + 1][bc] = v.y;
                xt[k4 + 2][bc] = v.z;
                xt[k4 + 3][bc] = v.w;
                // wt: same flat decomposition, direct copy (coalesced, 2-way-free writes)
                *(float4*)&wt[b][k4] = *(const float4*)&We_n[(size_t)(n0 + b) * 64 + j4 * 4];
            }
        } else {
#pragma unroll
            for (int r = 0; r < 4; r++) {
                int flat = r * 256 + t;
                int b  = flat >> 4;
                int j4 = flat & 15;
                int n  = n0 + j4 * 4;
                const float* xb = &x[(size_t)b * N_];
                float4 v = make_float4(0.f, 0.f, 0.f, 0.f);
                if (n + 3 < N_) v = *(const float4*)&xb[n];
                else {
                    if (n + 0 < N_) v.x = xb[n + 0];
                    if (n + 1 < N_) v.y = xb[n + 1];
                    if (n + 2 < N_) v.z = xb[n + 2];
                    if (n + 3 < N_) v.w = xb[n + 3];
                }
                int bc = b ^ (((j4 ^ (j4 >> 2)) & 7) << 3);
                int k4 = j4 * 4;
                xt[k4 + 0][bc] = v.x;
                xt[k4 + 1][bc] = v.y;
                xt[k4 + 2][bc] = v.z;
                xt[k4 + 3][bc] = v.w;
                float4 w = make_float4(0.f, 0.f, 0.f, 0.f);
                if (n0 + b < N_) w = *(const float4*)&We_n[(size_t)(n0 + b) * 64 + j4 * 4];
                *(float4*)&wt[b][j4 * 4] = w;
            }
        }
        __syncthreads();
        int kb = wv * 16;                  // per-wave K-slice of the chunk
#pragma unroll 2
        for (int kk = 0; kk < 16; kk++) {
            int k = kb + kk;
            int sw = (((k >> 2) ^ (k >> 4)) & 7) << 3;
            const float* xr = &xt[k][(lb * 8) ^ sw];
            float4 xa0 = *(const float4*)(xr);
            float4 xa1 = *(const float4*)(xr + 4);
            const float* wr = &wt[k][ll * 8];
            float4 wa0 = *(const float4*)(wr);
            float4 wa1 = *(const float4*)(wr + 4);
            float xs[8] = {xa0.x, xa0.y, xa0.z, xa0.w, xa1.x, xa1.y, xa1.z, xa1.w};
            float wsv[8] = {wa0.x, wa0.y, wa0.z, wa0.w, wa1.x, wa1.y, wa1.z, wa1.w};
#pragma unroll
            for (int i = 0; i < 8; i++)
#pragma unroll
                for (int j = 0; j < 8; j++)
                    acc[i * 8 + j] += xs[i] * wsv[j];
        }
    }

    // Cross-wave reduction through LDS (reuse tile buffers), halves of acc.
    float* r0 = &xt[0][0];                 // 4352 floats available
    float* r1 = &wt[0][0];                 // 4096 floats available
#pragma unroll
    for (int h = 0; h < 2; h++) {
        __syncthreads();
        if (wv == 1) {
#pragma unroll
            for (int q = 0; q < 32; q++) r0[q * 64 + lane] = acc[h * 32 + q];
        } else if (wv == 2) {
#pragma unroll
            for (int q = 0; q < 32; q++) r0[2048 + q * 64 + lane] = acc[h * 32 + q];
        } else if (wv == 3) {
#pragma unroll
            for (int q = 0; q < 32; q++) r1[q * 64 + lane] = acc[h * 32 + q];
        }
        __syncthreads();
        if (wv == 0) {
#pragma unroll
            for (int q = 0; q < 32; q++)
                acc[h * 32 + q] += r0[q * 64 + lane] + r0[2048 + q * 64 + lane] + r1[q * 64 + lane];
        }
    }

    if (wv == 0) {
        int row = blockIdx.x & 63;
        float* zr = &zp2[row * 4096];
#pragma unroll
        for (int i = 0; i < 8; i++) {
            int b = lb * 8 + i;
#pragma unroll
            for (int j = 0; j < 8; j++) {
                int l = ll * 8 + j;
                atomicAdd(&zr[l * 64 + b], acc[i * 8 + j]);
            }
        }
    }
}

// K7: z2g[l*64+b] = sum_rows zp2 + be[l].
__global__ void k_zred(const float* __restrict__ zp2, const float* __restrict__ be_m,
                       float* __restrict__ z2g) {
    int slot = blockIdx.x * 256 + threadIdx.x;   // 16 blocks x 256
    float s = 0.f;
    for (int r = 0; r < 64; r++) s += zp2[r * 4096 + slot];
    z2g[slot] = s + be_m[slot >> 6];
}

// ---------------------------------------------------------------------------
// K8: P[m,b] = sum_l z2g[l*64+b] * Wd_m[l,m] + bd_m[m].  P layout [S][64].
// Wd_m read coalesced (thread = m); z2g via uniform s_loads (no LDS).
__global__ __launch_bounds__(256) void k_pmat(
        const float* __restrict__ Wd_m, const float* __restrict__ bd_m,
        const float* __restrict__ z2g, float* __restrict__ P) {
    int m = blockIdx.x * 256 + threadIdx.x;
    if (m >= S_) return;
    float bd = bd_m[m];
    float acc[64];
#pragma unroll
    for (int b = 0; b < 64; b++) acc[b] = bd;
    for (int l = 0; l < 64; l++) {
        float w = Wd_m[(size_t)l * S_ + m];            // coalesced
        const float* zr = z2g + l * 64;                // uniform -> s_load
#pragma unroll
        for (int g = 0; g < 4; g++) {
#pragma unroll
            for (int q = 0; q < 16; q++)
                acc[g * 16 + q] += w * zr[g * 16 + q];
        }
    }
    float4* Pv = (float4*)(&P[(size_t)m * 64]);
#pragma unroll
    for (int q = 0; q < 16; q++)
        Pv[q] = make_float4(acc[q * 4 + 0], acc[q * 4 + 1], acc[q * 4 + 2], acc[q * 4 + 3]);
}

// ---------------------------------------------------------------------------
// K9: out[b,j] = (sum_{m in elist(j)} P[m,b]) / max(ecnt[j],1).
// Wave serves its 16 jj's in 4 groups of 4 concurrent segments (4x MLP).
// lane = b; 64-j tile through LDS for coalesced out writes.
__global__ __launch_bounds__(256) void k_decode(const float* __restrict__ P,
        const int* __restrict__ ecnt, const int* __restrict__ offs,
        const int* __restrict__ elist, float* __restrict__ out) {
    __shared__ float tile[64][65];
    int t = threadIdx.x;
    int wv = t >> 6, lane = t & 63;
    int j0 = blockIdx.x * 64;
    for (int g = 0; g < 4; g++) {
        int jjb = wv * 16 + g * 4;
        int c[4], o[4];
        float acc[4];
#pragma unroll
        for (int s = 0; s < 4; s++) {
            int j = j0 + jjb + s;
            bool v = (j < N_);
            c[s] = v ? ecnt[j] : 0;
            o[s] = v ? offs[j] : 0;
            acc[s] = 0.f;
        }
        int cmax = max(max(c[0], c[1]), max(c[2], c[3]));
        for (int q = 0; q < cmax; q++) {
            int mm[4];
#pragma unroll
            for (int s = 0; s < 4; s++)
                mm[s] = (q < c[s]) ? elist[o[s] + q] : -1;  // 4 independent broadcast loads
#pragma unroll
            for (int s = 0; s < 4; s++)
                if (mm[s] >= 0) acc[s] += P[(size_t)mm[s] * 64 + lane]; // 4 row gathers in flight
        }
#pragma unroll
        for (int s = 0; s < 4; s++) {
            int cc = (c[s] > 1) ? c[s] : 1;
            tile[jjb + s][lane] = acc[s] * (1.0f / (float)cc);
        }
    }
    __syncthreads();
#pragma unroll
    for (int r = 0; r < 16; r++) {
        int b = r * 4 + wv;
        int j = j0 + lane;
        if (j < N_) out[(size_t)b * N_ + j] = tile[lane][b];
    }
}

// ---------------------------------------------------------------------------
extern "C" void kernel_launch(void* const* d_in, const int* in_sizes, int n_in,
                              void* d_out, int out_size, void* d_ws, size_t ws_size,
                              hipStream_t stream) {
    const float* We_m = (const float*)d_in[0];
    const float* be_m = (const float*)d_in[1];
    const float* Wd_m = (const float*)d_in[2];
    const float* bd_m = (const float*)d_in[3];
    const float* x    = (const float*)d_in[4];
    const int*   nn_n = (const int*)d_in[5];
    const int*   nn_m = (const int*)d_in[6];
    float* out = (float*)d_out;
    char* ws = (char*)d_ws;

    // Workspace layout (byte offsets). Region 0 holds We_n [N,64] during the
    // encode phase, then is reused for P [S,64] in the decode phase.
    float* We_n  = (float*)(ws + 0);           // 64,000,000 B
    float* P     = (float*)(ws + 0);           // 51,200,000 B (aliases We_n; phase-ordered)
    int*   c_m   = (int*)(ws + 64000000);      //    800,000 B (zeroed)
    int*   ecnt  = (int*)(ws + 64800000);      //  1,000,000 B (zeroed)
    int*   fill  = (int*)(ws + 65800000);      //  1,000,000 B (zeroed)
    int*   added = (int*)(ws + 66800000);      //  1,000,000 B
    int*   offs  = (int*)(ws + 67800000);      //  1,000,000 B
    int*   elist = (int*)(ws + 68800000);      //  2,000,000 B (<= (S+N)*4 = 1.8 MB)
    float* zp2   = (float*)(ws + 70800000);    //  1,048,576 B (64 x 4096, zeroed)
    float* z2g   = (float*)(ws + 71848576);    //     16,384 B
    int*   bsum  = (int*)(ws + 71864960);      //      1,024 B
    // total ~71.9 MB

    hipMemsetAsync(ws + 64000000, 0, 2800000, stream);   // c_m, ecnt, fill
    hipMemsetAsync(zp2, 0, 1048576, stream);             // zp2

    k_added_counts<<<977, 256, 0, stream>>>(nn_n, nn_m, added, c_m, ecnt);
    k_scan_blocksum<<<245, 256, 0, stream>>>(ecnt, bsum);
    k_scan_apply<<<245, 256, 0, stream>>>(ecnt, bsum, offs);
    k_fill<<<977, 256, 0, stream>>>(nn_m, nn_n, added, offs, fill, elist);
    k_wen<<<15625, 256, 0, stream>>>(We_m, c_m, ecnt, offs, elist, We_n);
    k_encode<<<ENC_GRID, 256, 0, stream>>>(x, We_n, zp2);
    k_zred<<<16, 256, 0, stream>>>(zp2, be_m, z2g);
    k_pmat<<<782, 256, 0, stream>>>(Wd_m, bd_m, z2g, P);
    k_decode<<<3907, 256, 0, stream>>>(P, ecnt, offs, elist, out);
}

// Round 2
// 437.809 us; speedup vs baseline: 1.1949x; 1.1949x over previous
//
#include <hip/hip_runtime.h>

// Problem constants (match reference)
constexpr int S_ = 200000;   // master nodes
constexpr int N_ = 250000;   // new nodes
// L = B = 64

constexpr int NCHUNK = (N_ + 63) / 64;   // 3907
constexpr int ENC_BLOCKS = (NCHUNK + 3) / 4;  // 977, 4 chunks per block

typedef __attribute__((ext_vector_type(8))) short bf16x8;
typedef __attribute__((ext_vector_type(4))) float f32x4;

// ---------------------------------------------------------------------------
// K1: added[n] = (nn_m[nn_n[n]] != n); c_m histogram (added only, over nn_n);
//     ecnt[j] = #masters with nn_m=j  +  added[j]  (extended segment size).
__global__ void k_added_counts(const int* __restrict__ nn_n, const int* __restrict__ nn_m,
                               int* __restrict__ added, int* __restrict__ c_m,
                               int* __restrict__ ecnt) {
    int i = blockIdx.x * 256 + threadIdx.x;
    if (i < N_) {
        int m = nn_n[i];
        int a = (nn_m[m] != i) ? 1 : 0;
        added[i] = a;
        if (a) {
            atomicAdd(&c_m[m], 1);
            atomicAdd(&ecnt[i], 1);
        }
    }
    if (i < S_) {
        atomicAdd(&ecnt[nn_m[i]], 1);
    }
}

// ---------------------------------------------------------------------------
// K2: per-block sums of ecnt (1024 elements / block) for the exclusive scan.
__global__ void k_scan_blocksum(const int* __restrict__ ecnt, int* __restrict__ bsum) {
    __shared__ int sd[256];
    int b = blockIdx.x, t = threadIdx.x;
    int base = b * 1024 + t * 4;
    int s = 0;
#pragma unroll
    for (int k = 0; k < 4; k++) { int idx = base + k; if (idx < N_) s += ecnt[idx]; }
    sd[t] = s;
    __syncthreads();
    for (int off = 128; off > 0; off >>= 1) {
        if (t < off) sd[t] += sd[t + off];
        __syncthreads();
    }
    if (t == 0) bsum[b] = sd[0];
}

// K3: exclusive scan -> offs.
__global__ void k_scan_apply(const int* __restrict__ ecnt, const int* __restrict__ bsum,
                             int* __restrict__ offs) {
    __shared__ int sd[256];
    __shared__ int sp[256];
    int b = blockIdx.x, t = threadIdx.x;
    sp[t] = (t < b) ? bsum[t] : 0;
    __syncthreads();
    for (int off = 128; off > 0; off >>= 1) {
        if (t < off) sp[t] += sp[t + off];
        __syncthreads();
    }
    int prev = sp[0];

    int base = b * 1024 + t * 4;
    int v[4]; int s = 0;
#pragma unroll
    for (int k = 0; k < 4; k++) { int idx = base + k; v[k] = (idx < N_) ? ecnt[idx] : 0; s += v[k]; }
    sd[t] = s;
    __syncthreads();
    for (int off = 1; off < 256; off <<= 1) {
        int xv = (t >= off) ? sd[t - off] : 0;
        __syncthreads();
        sd[t] += xv;
        __syncthreads();
    }
    int run = prev + sd[t] - s;
#pragma unroll
    for (int k = 0; k < 4; k++) {
        int idx = base + k;
        if (idx < N_) offs[idx] = run;
        run += v[k];
    }
}

// K4: extended CSR fill — masters (nn_m inverse) plus the added contributor
//     nn_n[j] appended to segment j.
__global__ void k_fill(const int* __restrict__ nn_m, const int* __restrict__ nn_n,
                       const int* __restrict__ added, const int* __restrict__ offs,
                       int* __restrict__ fill, int* __restrict__ elist) {
    int i = blockIdx.x * 256 + threadIdx.x;
    if (i < S_) {
        int j = nn_m[i];
        int p = atomicAdd(&fill[j], 1);
        elist[offs[j] + p] = i;
    }
    if (i < N_ && added[i]) {
        int p = atomicAdd(&fill[i], 1);
        elist[offs[i] + p] = nn_n[i];
    }
}

// ---------------------------------------------------------------------------
// K5: We_n[j,:] = sum_{m in elist(j)} We_m[m,:] / (c_m[m]+1).
// One wave serves FOUR segments concurrently (4 gathers in flight -> 4x MLP).
// lane = column; all control flow is wave-uniform.
// NEW: result is written as hi/lo bf16 split, directly in MFMA-fragment order
// (buffer Wf), so k_encode reads perfectly linear b128 fragments.
// Wf layout (ushort): [(chunk*2+s)*4096 + ct*1024 + hl*512 + lane'*8 + i]
//   where for element (j,l): chunk=j>>6, k=j&63, s=k>>5, kq=(k>>3)&3, i=k&7,
//   ct=l>>4, lane'=(l&15)+16*kq.  Each 512-ushort block = one B-fragment set.
__global__ __launch_bounds__(256) void k_wen(
        const float* __restrict__ We_m, const int* __restrict__ c_m,
        const int* __restrict__ ecnt, const int* __restrict__ offs,
        const int* __restrict__ elist, unsigned short* __restrict__ Wf) {
    int t = threadIdx.x;
    int lane = t & 63;
    int wid = blockIdx.x * 4 + (t >> 6);
    int jb = wid * 4;                     // 4 segments per wave
    if (jb >= N_) return;
    int c[4], o[4];
    float acc[4];
#pragma unroll
    for (int s = 0; s < 4; s++) {
        int j = jb + s;
        bool v = (j < N_);
        c[s] = v ? ecnt[j] : 0;
        o[s] = v ? offs[j] : 0;
        acc[s] = 0.f;
    }
    int cmax = max(max(c[0], c[1]), max(c[2], c[3]));
    for (int q = 0; q < cmax; q++) {
        int mm[4];
#pragma unroll
        for (int s = 0; s < 4; s++)
            mm[s] = (q < c[s]) ? elist[o[s] + q] : -1;   // 4 independent broadcast loads
        float row[4], sc[4];
#pragma unroll
        for (int s = 0; s < 4; s++) {
            if (mm[s] >= 0) {
                row[s] = We_m[(size_t)mm[s] * 64 + lane]; // 4 independent row gathers
                sc[s]  = 1.0f / (float)(c_m[mm[s]] + 1);
            }
        }
#pragma unroll
        for (int s = 0; s < 4; s++)
            if (mm[s] >= 0) acc[s] += row[s] * sc[s];
    }
    int ct  = lane >> 4;
    int l15 = lane & 15;
#pragma unroll
    for (int s2 = 0; s2 < 4; s2++) {
        int j = jb + s2;
        if (j < N_) {
            float v = acc[s2];
            unsigned u = __float_as_uint(v);
            unsigned short hi = (unsigned short)(u >> 16);
            float r = v - __uint_as_float(u & 0xffff0000u);
            unsigned short lo = (unsigned short)(__float_as_uint(r) >> 16);
            int ch = j >> 6, k = j & 63;
            int s = k >> 5, kq2 = (k >> 3) & 3, i = k & 7;
            size_t base = ((size_t)ch * 2 + s) * 4096 + (size_t)ct * 1024
                        + (size_t)(l15 + 16 * kq2) * 8 + i;
            Wf[base]       = hi;     // hl = 0
            Wf[base + 512] = lo;     // hl = 1
        }
    }
}

// ---------------------------------------------------------------------------
// K6: encode GEMM z[b,l] = sum_n x[b,n]*We_n[n,l]  via MFMA.
// fp32 emulated with bf16 hi/lo split: a*b ~= ah*bh + al*bh + ah*bl.
// No LDS, no barriers. Wave wv owns rows [16wv,16wv+16) (disjoint A bands);
// A fragments load straight from x in native MFMA layout (lane&15 = row,
// 8 contiguous k per lane = 32B). B fragments come pre-split/pre-swizzled
// from Wf (linear lane*16B loads); 4 waves share them via L1/L2.
// Epilogue: dense atomicAdd (16 consecutive floats per lane-quad) into
// zp2[row][b*64+l]  -> 64 touched lines per wave (memory-side atomics).
__global__ __launch_bounds__(256) void k_encode(const float* __restrict__ x,
        const unsigned short* __restrict__ Wf, float* __restrict__ zp2) {
    int t = threadIdx.x;
    int lane = t & 63;
    int wv = t >> 6;                 // row band
    int mrow = lane & 15;            // A row within band / C col
    int kq = lane >> 4;              // A k-quad / C row-quad
    const float* xbase = x + (size_t)(wv * 16 + mrow) * N_ + kq * 8;
    f32x4 acc[4];
#pragma unroll
    for (int ct = 0; ct < 4; ct++) acc[ct] = (f32x4){0.f, 0.f, 0.f, 0.f};

    for (int cc = 0; cc < 4; cc++) {
        int c = blockIdx.x * 4 + cc;
        if (c >= NCHUNK) break;
        int n0 = c * 64;
#pragma unroll
        for (int s = 0; s < 2; s++) {
            // ---- A raw load (8 consecutive fp32 along k), tail-guarded ----
            float av[8];
            if (n0 + s * 32 + kq * 8 + 8 <= N_) {
                float4 a0 = *(const float4*)(xbase + n0 + s * 32);
                float4 a1 = *(const float4*)(xbase + n0 + s * 32 + 4);
                av[0] = a0.x; av[1] = a0.y; av[2] = a0.z; av[3] = a0.w;
                av[4] = a1.x; av[5] = a1.y; av[6] = a1.z; av[7] = a1.w;
            } else {
#pragma unroll
                for (int i = 0; i < 8; i++) av[i] = 0.f;
            }
            // ---- B fragments: linear, coalesced, already bf16 hi/lo ----
            const bf16x8* bp = (const bf16x8*)Wf + ((size_t)c * 2 + s) * 512 + lane;
            bf16x8 bh[4], bl[4];
#pragma unroll
            for (int ct = 0; ct < 4; ct++) {
                bh[ct] = bp[ct * 128];
                bl[ct] = bp[ct * 128 + 64];
            }
            // ---- split A into hi/lo bf16 ----
            bf16x8 ah, al;
#pragma unroll
            for (int i = 0; i < 8; i++) {
                float v = av[i];
                unsigned u = __float_as_uint(v);
                ah[i] = (short)(u >> 16);
                float r = v - __uint_as_float(u & 0xffff0000u);
                al[i] = (short)(__float_as_uint(r) >> 16);
            }
            // ---- 12 MFMAs: 4 col-tiles x 3 split terms ----
#pragma unroll
            for (int ct = 0; ct < 4; ct++) {
                acc[ct] = __builtin_amdgcn_mfma_f32_16x16x32_bf16(ah, bh[ct], acc[ct], 0, 0, 0);
                acc[ct] = __builtin_amdgcn_mfma_f32_16x16x32_bf16(al, bh[ct], acc[ct], 0, 0, 0);
                acc[ct] = __builtin_amdgcn_mfma_f32_16x16x32_bf16(ah, bl[ct], acc[ct], 0, 0, 0);
            }
        }
    }

    // Epilogue: C/D layout col=lane&15, row=(lane>>4)*4+reg (verified m89).
    int row = blockIdx.x & 63;
    float* zr = zp2 + row * 4096;
#pragma unroll
    for (int ct = 0; ct < 4; ct++) {
#pragma unroll
        for (int r = 0; r < 4; r++) {
            int b = wv * 16 + kq * 4 + r;
            int l = ct * 16 + mrow;
            atomicAdd(&zr[b * 64 + l], acc[ct][r]);   // 16 consecutive floats/quad
        }
    }
}

// K7: z2g[l*64+b] = sum_rows zp2[b*64+l] + be[l].  (zp2 is b-major now)
__global__ void k_zred(const float* __restrict__ zp2, const float* __restrict__ be_m,
                       float* __restrict__ z2g) {
    int slot = blockIdx.x * 256 + threadIdx.x;   // 16 blocks x 256, slot = b*64+l
    float s = 0.f;
    for (int r = 0; r < 64; r++) s += zp2[r * 4096 + slot];
    int b = slot >> 6, l = slot & 63;
    z2g[l * 64 + b] = s + be_m[l];
}

// ---------------------------------------------------------------------------
// K8: P[m,b] = sum_l z2g[l*64+b] * Wd_m[l,m] + bd_m[m].  P layout [S][64].
// Wd_m read coalesced (thread = m); z2g via uniform s_loads (no LDS).
__global__ __launch_bounds__(256) void k_pmat(
        const float* __restrict__ Wd_m, const float* __restrict__ bd_m,
        const float* __restrict__ z2g, float* __restrict__ P) {
    int m = blockIdx.x * 256 + threadIdx.x;
    if (m >= S_) return;
    float bd = bd_m[m];
    float acc[64];
#pragma unroll
    for (int b = 0; b < 64; b++) acc[b] = bd;
    for (int l = 0; l < 64; l++) {
        float w = Wd_m[(size_t)l * S_ + m];            // coalesced
        const float* zr = z2g + l * 64;                // uniform -> s_load
#pragma unroll
        for (int g = 0; g < 4; g++) {
#pragma unroll
            for (int q = 0; q < 16; q++)
                acc[g * 16 + q] += w * zr[g * 16 + q];
        }
    }
    float4* Pv = (float4*)(&P[(size_t)m * 64]);
#pragma unroll
    for (int q = 0; q < 16; q++)
        Pv[q] = make_float4(acc[q * 4 + 0], acc[q * 4 + 1], acc[q * 4 + 2], acc[q * 4 + 3]);
}

// ---------------------------------------------------------------------------
// K9: out[b,j] = (sum_{m in elist(j)} P[m,b]) / max(ecnt[j],1).
// Wave serves its 16 jj's in 4 groups of 4 concurrent segments (4x MLP).
// lane = b; 64-j tile through LDS for coalesced out writes.
__global__ __launch_bounds__(256) void k_decode(const float* __restrict__ P,
        const int* __restrict__ ecnt, const int* __restrict__ offs,
        const int* __restrict__ elist, float* __restrict__ out) {
    __shared__ float tile[64][65];
    int t = threadIdx.x;
    int wv = t >> 6, lane = t & 63;
    int j0 = blockIdx.x * 64;
    for (int g = 0; g < 4; g++) {
        int jjb = wv * 16 + g * 4;
        int c[4], o[4];
        float acc[4];
#pragma unroll
        for (int s = 0; s < 4; s++) {
            int j = j0 + jjb + s;
            bool v = (j < N_);
            c[s] = v ? ecnt[j] : 0;
            o[s] = v ? offs[j] : 0;
            acc[s] = 0.f;
        }
        int cmax = max(max(c[0], c[1]), max(c[2], c[3]));
        for (int q = 0; q < cmax; q++) {
            int mm[4];
#pragma unroll
            for (int s = 0; s < 4; s++)
                mm[s] = (q < c[s]) ? elist[o[s] + q] : -1;  // 4 independent broadcast loads
#pragma unroll
            for (int s = 0; s < 4; s++)
                if (mm[s] >= 0) acc[s] += P[(size_t)mm[s] * 64 + lane]; // 4 row gathers in flight
        }
#pragma unroll
        for (int s = 0; s < 4; s++) {
            int cc = (c[s] > 1) ? c[s] : 1;
            tile[jjb + s][lane] = acc[s] * (1.0f / (float)cc);
        }
    }
    __syncthreads();
#pragma unroll
    for (int r = 0; r < 16; r++) {
        int b = r * 4 + wv;
        int j = j0 + lane;
        if (j < N_) out[(size_t)b * N_ + j] = tile[lane][b];
    }
}

// ---------------------------------------------------------------------------
extern "C" void kernel_launch(void* const* d_in, const int* in_sizes, int n_in,
                              void* d_out, int out_size, void* d_ws, size_t ws_size,
                              hipStream_t stream) {
    const float* We_m = (const float*)d_in[0];
    const float* be_m = (const float*)d_in[1];
    const float* Wd_m = (const float*)d_in[2];
    const float* bd_m = (const float*)d_in[3];
    const float* x    = (const float*)d_in[4];
    const int*   nn_n = (const int*)d_in[5];
    const int*   nn_m = (const int*)d_in[6];
    float* out = (float*)d_out;
    char* ws = (char*)d_ws;

    // Workspace layout (byte offsets). Region 0 holds Wf (pre-split bf16
    // We_n fragments, 3907*16384 = 64,012,288 B) during the encode phase,
    // then is reused for P [S,64] (51.2 MB) in the decode phase.
    unsigned short* Wf = (unsigned short*)(ws + 0);
    float* P     = (float*)(ws + 0);           // aliases Wf; phase-ordered
    int*   c_m   = (int*)(ws + 64012288);      //    800,000 B (zeroed)
    int*   ecnt  = (int*)(ws + 64812288);      //  1,000,000 B (zeroed)
    int*   fill  = (int*)(ws + 65812288);      //  1,000,000 B (zeroed)
    int*   added = (int*)(ws + 66812288);      //  1,000,000 B
    int*   offs  = (int*)(ws + 67812288);      //  1,000,000 B
    int*   elist = (int*)(ws + 68812288);      //  2,000,000 B (<= (S+N)*4 = 1.8 MB)
    float* zp2   = (float*)(ws + 70812288);    //  1,048,576 B (64 x 4096, zeroed)
    float* z2g   = (float*)(ws + 71860864);    //     16,384 B
    int*   bsum  = (int*)(ws + 71877248);      //      1,024 B
    // total ~71.9 MB

    hipMemsetAsync(ws + 64012288, 0, 2800000, stream);       // c_m, ecnt, fill
    hipMemsetAsync(zp2, 0, 1048576, stream);                 // zp2
    hipMemsetAsync(ws + (size_t)3906 * 16384, 0, 16384, stream); // Wf tail chunk pad

    k_added_counts<<<977, 256, 0, stream>>>(nn_n, nn_m, added, c_m, ecnt);
    k_scan_blocksum<<<245, 256, 0, stream>>>(ecnt, bsum);
    k_scan_apply<<<245, 256, 0, stream>>>(ecnt, bsum, offs);
    k_fill<<<977, 256, 0, stream>>>(nn_m, nn_n, added, offs, fill, elist);
    k_wen<<<15625, 256, 0, stream>>>(We_m, c_m, ecnt, offs, elist, Wf);
    k_encode<<<ENC_BLOCKS, 256, 0, stream>>>(x, Wf, zp2);
    k_zred<<<16, 256, 0, stream>>>(zp2, be_m, z2g);
    k_pmat<<<782, 256, 0, stream>>>(Wd_m, bd_m, z2g, P);
    k_decode<<<3907, 256, 0, stream>>>(P, ecnt, offs, elist, out);
}

// Round 3
// 404.573 us; speedup vs baseline: 1.2931x; 1.0822x over previous
//
#include <hip/hip_runtime.h>

// Problem constants (match reference)
constexpr int S_ = 200000;   // master nodes
constexpr int N_ = 250000;   // new nodes
// L = B = 64

constexpr int NCHUNK = (N_ + 63) / 64;   // 3907
constexpr int ENC_BLOCKS = (NCHUNK + 3) / 4;  // 977, 4 chunks per block

typedef __attribute__((ext_vector_type(8))) short bf16x8;
typedef __attribute__((ext_vector_type(4))) float f32x4;
typedef __attribute__((ext_vector_type(4))) unsigned short us4;
typedef __attribute__((ext_vector_type(8))) unsigned short us8;

// ---------------------------------------------------------------------------
// K1: added[n] = (nn_m[nn_n[n]] != n); c_m histogram (added only, over nn_n);
//     ecnt[j] = #masters with nn_m=j  +  added[j]  (extended segment size).
__global__ void k_added_counts(const int* __restrict__ nn_n, const int* __restrict__ nn_m,
                               int* __restrict__ added, int* __restrict__ c_m,
                               int* __restrict__ ecnt) {
    int i = blockIdx.x * 256 + threadIdx.x;
    if (i < N_) {
        int m = nn_n[i];
        int a = (nn_m[m] != i) ? 1 : 0;
        added[i] = a;
        if (a) {
            atomicAdd(&c_m[m], 1);
            atomicAdd(&ecnt[i], 1);
        }
    }
    if (i < S_) {
        atomicAdd(&ecnt[nn_m[i]], 1);
    }
}

// ---------------------------------------------------------------------------
// K2: per-block sums of ecnt (1024 elements / block) for the exclusive scan.
__global__ void k_scan_blocksum(const int* __restrict__ ecnt, int* __restrict__ bsum) {
    __shared__ int sd[256];
    int b = blockIdx.x, t = threadIdx.x;
    int base = b * 1024 + t * 4;
    int s = 0;
#pragma unroll
    for (int k = 0; k < 4; k++) { int idx = base + k; if (idx < N_) s += ecnt[idx]; }
    sd[t] = s;
    __syncthreads();
    for (int off = 128; off > 0; off >>= 1) {
        if (t < off) sd[t] += sd[t + off];
        __syncthreads();
    }
    if (t == 0) bsum[b] = sd[0];
}

// K3: exclusive scan -> offs.
__global__ void k_scan_apply(const int* __restrict__ ecnt, const int* __restrict__ bsum,
                             int* __restrict__ offs) {
    __shared__ int sd[256];
    __shared__ int sp[256];
    int b = blockIdx.x, t = threadIdx.x;
    sp[t] = (t < b) ? bsum[t] : 0;
    __syncthreads();
    for (int off = 128; off > 0; off >>= 1) {
        if (t < off) sp[t] += sp[t + off];
        __syncthreads();
    }
    int prev = sp[0];

    int base = b * 1024 + t * 4;
    int v[4]; int s = 0;
#pragma unroll
    for (int k = 0; k < 4; k++) { int idx = base + k; v[k] = (idx < N_) ? ecnt[idx] : 0; s += v[k]; }
    sd[t] = s;
    __syncthreads();
    for (int off = 1; off < 256; off <<= 1) {
        int xv = (t >= off) ? sd[t - off] : 0;
        __syncthreads();
        sd[t] += xv;
        __syncthreads();
    }
    int run = prev + sd[t] - s;
#pragma unroll
    for (int k = 0; k < 4; k++) {
        int idx = base + k;
        if (idx < N_) offs[idx] = run;
        run += v[k];
    }
}

// K4: extended CSR fill — masters (nn_m inverse) plus the added contributor
//     nn_n[j] appended to segment j.
__global__ void k_fill(const int* __restrict__ nn_m, const int* __restrict__ nn_n,
                       const int* __restrict__ added, const int* __restrict__ offs,
                       int* __restrict__ fill, int* __restrict__ elist) {
    int i = blockIdx.x * 256 + threadIdx.x;
    if (i < S_) {
        int j = nn_m[i];
        int p = atomicAdd(&fill[j], 1);
        elist[offs[j] + p] = i;
    }
    if (i < N_ && added[i]) {
        int p = atomicAdd(&fill[i], 1);
        elist[offs[i] + p] = nn_n[i];
    }
}

// ---------------------------------------------------------------------------
// K5: We_n[j,:] = sum_{m in elist(j)} We_m[m,:] / (c_m[m]+1).
// One wave serves FOUR segments concurrently; lane = column l.
// Support loads (ecnt/offs/elist/c_m) are readfirstlane'd -> scalar s_load
// chain on the SMEM path; vector path carries only We_m row gathers.
// Epilogue: a block's 16 j's cover a DENSE 4 KB Wf sub-region (8 x 512 B
// pieces; ch/s/kqb are block-uniform) -> stage hi/lo bf16 in a 4 KB LDS
// image, one barrier, one coalesced 16 B store per thread.
// Wf layout (ushort): [(ch*2+s)*4096 + ct*1024 + hl*512 + (l15+16*kq2)*8 + i]
//   for element (j,l): ch=j>>6, k=j&63, s=k>>5, kq2=(k>>3)&3, i=k&7,
//   ct=l>>4, l15=l&15.
__global__ __launch_bounds__(256) void k_wen(
        const float* __restrict__ We_m, const int* __restrict__ c_m,
        const int* __restrict__ ecnt, const int* __restrict__ offs,
        const int* __restrict__ elist, unsigned short* __restrict__ Wf) {
    __shared__ unsigned short sw[2048];       // 4 KB dense block image
    int t = threadIdx.x;
    int lane = t & 63;
    int wv = __builtin_amdgcn_readfirstlane(t >> 6);
    int jb = (blockIdx.x * 4 + wv) * 4;       // 4 segments per wave; always < N_
    int c[4], o[4];
    float acc[4];
#pragma unroll
    for (int s = 0; s < 4; s++) {
        int j = jb + s;
        c[s] = __builtin_amdgcn_readfirstlane(ecnt[j]);
        o[s] = __builtin_amdgcn_readfirstlane(offs[j]);
        acc[s] = 0.f;
    }
    int cmax = max(max(c[0], c[1]), max(c[2], c[3]));
    for (int q = 0; q < cmax; q++) {
        int mm[4];
#pragma unroll
        for (int s = 0; s < 4; s++)
            mm[s] = (q < c[s]) ? __builtin_amdgcn_readfirstlane(elist[o[s] + q]) : -1;
        float row[4], sc[4];
#pragma unroll
        for (int s = 0; s < 4; s++) {
            if (mm[s] >= 0) {
                row[s] = We_m[(size_t)mm[s] * 64 + lane]; // 4 independent row gathers
                sc[s]  = 1.0f / (float)(c_m[mm[s]] + 1);  // scalar load (uniform)
            }
        }
#pragma unroll
        for (int s = 0; s < 4; s++)
            if (mm[s] >= 0) acc[s] += row[s] * sc[s];
    }

    // ---- epilogue: hi/lo bf16 split -> LDS image -> dense cooperative store
    int ct  = lane >> 4;
    int l15 = lane & 15;
    int k0  = jb & 63;                 // wave-uniform; 4-aligned
    int i0  = k0 & 7;                  // 0 or 4
    int kq2p = (k0 >> 3) & 1;          // local half within block region
    int lbase = ct * 512 + (l15 + 16 * kq2p) * 8 + i0;   // hl=0 slot
    us4 hv, lv;
#pragma unroll
    for (int s2 = 0; s2 < 4; s2++) {
        float v = acc[s2];
        unsigned u = __float_as_uint(v);
        hv[s2] = (unsigned short)(u >> 16);
        float r = v - __uint_as_float(u & 0xffff0000u);
        lv[s2] = (unsigned short)(__float_as_uint(r) >> 16);
    }
    *(us4*)&sw[lbase]       = hv;
    *(us4*)&sw[lbase + 256] = lv;
    __syncthreads();
    int ch  = jb >> 6;                 // block-uniform
    int sH  = (k0 >> 5) & 1;           // block-uniform
    int kqb = (k0 >> 3) & 2;           // block-uniform
    size_t R = ((size_t)ch * 2 + sH) * 4096 + (size_t)kqb * 128;
    size_t g = R + (size_t)(t >> 6) * 1024 + (size_t)((t >> 5) & 1) * 512
                 + (size_t)(t & 31) * 8;
    *(us8*)(Wf + g) = *(const us8*)&sw[t * 8];   // 16 B coalesced
}

// ---------------------------------------------------------------------------
// K6: encode GEMM z[b,l] = sum_n x[b,n]*We_n[n,l]  via MFMA.
// fp32 emulated with bf16 hi/lo split: a*b ~= ah*bh + al*bh + ah*bl.
// No LDS, no barriers. Wave wv owns rows [16wv,16wv+16) (disjoint A bands);
// A fragments load straight from x in native MFMA layout. B fragments come
// pre-split/pre-swizzled from Wf (linear lane*16B loads); shared via L1/L2.
// Epilogue: dense atomicAdd into zp2[row][b*64+l].
__global__ __launch_bounds__(256) void k_encode(const float* __restrict__ x,
        const unsigned short* __restrict__ Wf, float* __restrict__ zp2) {
    int t = threadIdx.x;
    int lane = t & 63;
    int wv = t >> 6;                 // row band
    int mrow = lane & 15;            // A row within band / C col
    int kq = lane >> 4;              // A k-quad / C row-quad
    const float* xbase = x + (size_t)(wv * 16 + mrow) * N_ + kq * 8;
    f32x4 acc[4];
#pragma unroll
    for (int ct = 0; ct < 4; ct++) acc[ct] = (f32x4){0.f, 0.f, 0.f, 0.f};

    for (int cc = 0; cc < 4; cc++) {
        int c = blockIdx.x * 4 + cc;
        if (c >= NCHUNK) break;
        int n0 = c * 64;
#pragma unroll
        for (int s = 0; s < 2; s++) {
            // ---- A raw load (8 consecutive fp32 along k), tail-guarded ----
            float av[8];
            if (n0 + s * 32 + kq * 8 + 8 <= N_) {
                float4 a0 = *(const float4*)(xbase + n0 + s * 32);
                float4 a1 = *(const float4*)(xbase + n0 + s * 32 + 4);
                av[0] = a0.x; av[1] = a0.y; av[2] = a0.z; av[3] = a0.w;
                av[4] = a1.x; av[5] = a1.y; av[6] = a1.z; av[7] = a1.w;
            } else {
#pragma unroll
                for (int i = 0; i < 8; i++) av[i] = 0.f;
            }
            // ---- B fragments: linear, coalesced, already bf16 hi/lo ----
            const bf16x8* bp = (const bf16x8*)Wf + ((size_t)c * 2 + s) * 512 + lane;
            bf16x8 bh[4], bl[4];
#pragma unroll
            for (int ct = 0; ct < 4; ct++) {
                bh[ct] = bp[ct * 128];
                bl[ct] = bp[ct * 128 + 64];
            }
            // ---- split A into hi/lo bf16 ----
            bf16x8 ah, al;
#pragma unroll
            for (int i = 0; i < 8; i++) {
                float v = av[i];
                unsigned u = __float_as_uint(v);
                ah[i] = (short)(u >> 16);
                float r = v - __uint_as_float(u & 0xffff0000u);
                al[i] = (short)(__float_as_uint(r) >> 16);
            }
            // ---- 12 MFMAs: 4 col-tiles x 3 split terms ----
#pragma unroll
            for (int ct = 0; ct < 4; ct++) {
                acc[ct] = __builtin_amdgcn_mfma_f32_16x16x32_bf16(ah, bh[ct], acc[ct], 0, 0, 0);
                acc[ct] = __builtin_amdgcn_mfma_f32_16x16x32_bf16(al, bh[ct], acc[ct], 0, 0, 0);
                acc[ct] = __builtin_amdgcn_mfma_f32_16x16x32_bf16(ah, bl[ct], acc[ct], 0, 0, 0);
            }
        }
    }

    // Epilogue: C/D layout col=lane&15, row=(lane>>4)*4+reg (verified m89).
    int row = blockIdx.x & 63;
    float* zr = zp2 + row * 4096;
#pragma unroll
    for (int ct = 0; ct < 4; ct++) {
#pragma unroll
        for (int r = 0; r < 4; r++) {
            int b = wv * 16 + kq * 4 + r;
            int l = ct * 16 + mrow;
            atomicAdd(&zr[b * 64 + l], acc[ct][r]);   // 16 consecutive floats/quad
        }
    }
}

// K7: z2g[l*64+b] = sum_rows zp2[b*64+l] + be[l].  (zp2 is b-major)
__global__ void k_zred(const float* __restrict__ zp2, const float* __restrict__ be_m,
                       float* __restrict__ z2g) {
    int slot = blockIdx.x * 256 + threadIdx.x;   // 16 blocks x 256, slot = b*64+l
    float s = 0.f;
    for (int r = 0; r < 64; r++) s += zp2[r * 4096 + slot];
    int b = slot >> 6, l = slot & 63;
    z2g[l * 64 + b] = s + be_m[l];
}

// ---------------------------------------------------------------------------
// K8: P[m,b] = sum_l z2g[l*64+b] * Wd_m[l,m] + bd_m[m].  P layout [S][64].
// Wd_m read coalesced (thread = m); z2g via uniform s_loads (no LDS).
__global__ __launch_bounds__(256) void k_pmat(
        const float* __restrict__ Wd_m, const float* __restrict__ bd_m,
        const float* __restrict__ z2g, float* __restrict__ P) {
    int m = blockIdx.x * 256 + threadIdx.x;
    if (m >= S_) return;
    float bd = bd_m[m];
    float acc[64];
#pragma unroll
    for (int b = 0; b < 64; b++) acc[b] = bd;
    for (int l = 0; l < 64; l++) {
        float w = Wd_m[(size_t)l * S_ + m];            // coalesced
        const float* zr = z2g + l * 64;                // uniform -> s_load
#pragma unroll
        for (int g = 0; g < 4; g++) {
#pragma unroll
            for (int q = 0; q < 16; q++)
                acc[g * 16 + q] += w * zr[g * 16 + q];
        }
    }
    float4* Pv = (float4*)(&P[(size_t)m * 64]);
#pragma unroll
    for (int q = 0; q < 16; q++)
        Pv[q] = make_float4(acc[q * 4 + 0], acc[q * 4 + 1], acc[q * 4 + 2], acc[q * 4 + 3]);
}

// ---------------------------------------------------------------------------
// K9: out[b,j] = (sum_{m in elist(j)} P[m,b]) / max(ecnt[j],1).
// Wave serves its 16 jj's in 4 groups of 4 concurrent segments.
// Support loads readfirstlane'd (scalar chain); lane = b; 64-j tile through
// LDS for coalesced out writes.
__global__ __launch_bounds__(256) void k_decode(const float* __restrict__ P,
        const int* __restrict__ ecnt, const int* __restrict__ offs,
        const int* __restrict__ elist, float* __restrict__ out) {
    __shared__ float tile[64][65];
    int t = threadIdx.x;
    int wv = __builtin_amdgcn_readfirstlane(t >> 6);
    int lane = t & 63;
    int j0 = blockIdx.x * 64;
    for (int g = 0; g < 4; g++) {
        int jjb = wv * 16 + g * 4;
        int c[4], o[4];
        float acc[4];
#pragma unroll
        for (int s = 0; s < 4; s++) {
            int j = j0 + jjb + s;
            bool v = (j < N_);
            c[s] = v ? __builtin_amdgcn_readfirstlane(ecnt[j]) : 0;
            o[s] = v ? __builtin_amdgcn_readfirstlane(offs[j]) : 0;
            acc[s] = 0.f;
        }
        int cmax = max(max(c[0], c[1]), max(c[2], c[3]));
        for (int q = 0; q < cmax; q++) {
            int mm[4];
#pragma unroll
            for (int s = 0; s < 4; s++)
                mm[s] = (q < c[s]) ? __builtin_amdgcn_readfirstlane(elist[o[s] + q]) : -1;
#pragma unroll
            for (int s = 0; s < 4; s++)
                if (mm[s] >= 0) acc[s] += P[(size_t)mm[s] * 64 + lane]; // 4 row gathers in flight
        }
#pragma unroll
        for (int s = 0; s < 4; s++) {
            int cc = (c[s] > 1) ? c[s] : 1;
            tile[jjb + s][lane] = acc[s] * (1.0f / (float)cc);
        }
    }
    __syncthreads();
#pragma unroll
    for (int r = 0; r < 16; r++) {
        int b = r * 4 + wv;
        int j = j0 + lane;
        if (j < N_) out[(size_t)b * N_ + j] = tile[lane][b];
    }
}

// ---------------------------------------------------------------------------
extern "C" void kernel_launch(void* const* d_in, const int* in_sizes, int n_in,
                              void* d_out, int out_size, void* d_ws, size_t ws_size,
                              hipStream_t stream) {
    const float* We_m = (const float*)d_in[0];
    const float* be_m = (const float*)d_in[1];
    const float* Wd_m = (const float*)d_in[2];
    const float* bd_m = (const float*)d_in[3];
    const float* x    = (const float*)d_in[4];
    const int*   nn_n = (const int*)d_in[5];
    const int*   nn_m = (const int*)d_in[6];
    float* out = (float*)d_out;
    char* ws = (char*)d_ws;

    // Workspace layout (byte offsets). Region 0 holds Wf (pre-split bf16
    // We_n fragments, 3907*16384 = 64,012,288 B) during the encode phase,
    // then is reused for P [S,64] (51.2 MB) in the decode phase.
    unsigned short* Wf = (unsigned short*)(ws + 0);
    float* P     = (float*)(ws + 0);           // aliases Wf; phase-ordered
    int*   c_m   = (int*)(ws + 64012288);      //    800,000 B (zeroed)
    int*   ecnt  = (int*)(ws + 64812288);      //  1,000,000 B (zeroed)
    int*   fill  = (int*)(ws + 65812288);      //  1,000,000 B (zeroed)
    int*   added = (int*)(ws + 66812288);      //  1,000,000 B
    int*   offs  = (int*)(ws + 67812288);      //  1,000,000 B
    int*   elist = (int*)(ws + 68812288);      //  2,000,000 B (<= (S+N)*4 = 1.8 MB)
    float* zp2   = (float*)(ws + 70812288);    //  1,048,576 B (64 x 4096, zeroed)
    float* z2g   = (float*)(ws + 71860864);    //     16,384 B
    int*   bsum  = (int*)(ws + 71877248);      //      1,024 B
    // total ~71.9 MB

    hipMemsetAsync(ws + 64012288, 0, 2800000, stream);       // c_m, ecnt, fill
    hipMemsetAsync(zp2, 0, 1048576, stream);                 // zp2
    hipMemsetAsync(ws + (size_t)3906 * 16384, 0, 16384, stream); // Wf tail chunk pad

    k_added_counts<<<977, 256, 0, stream>>>(nn_n, nn_m, added, c_m, ecnt);
    k_scan_blocksum<<<245, 256, 0, stream>>>(ecnt, bsum);
    k_scan_apply<<<245, 256, 0, stream>>>(ecnt, bsum, offs);
    k_fill<<<977, 256, 0, stream>>>(nn_m, nn_n, added, offs, fill, elist);
    k_wen<<<15625, 256, 0, stream>>>(We_m, c_m, ecnt, offs, elist, Wf);
    k_encode<<<ENC_BLOCKS, 256, 0, stream>>>(x, Wf, zp2);
    k_zred<<<16, 256, 0, stream>>>(zp2, be_m, z2g);
    k_pmat<<<782, 256, 0, stream>>>(Wd_m, bd_m, z2g, P);
    k_decode<<<3907, 256, 0, stream>>>(P, ecnt, offs, elist, out);
}

// Round 4
// 366.390 us; speedup vs baseline: 1.4278x; 1.1042x over previous
//
#include <hip/hip_runtime.h>

// Problem constants (match reference)
constexpr int S_ = 200000;   // master nodes
constexpr int N_ = 250000;   // new nodes
// L = B = 64

constexpr int NCHUNK = (N_ + 63) / 64;   // 3907
constexpr int ENC_BLOCKS = (NCHUNK + 3) / 4;  // 977, 4 chunks per block

typedef __attribute__((ext_vector_type(8))) short bf16x8;
typedef __attribute__((ext_vector_type(4))) float f32x4;
typedef __attribute__((ext_vector_type(4))) unsigned short us4;
typedef __attribute__((ext_vector_type(8))) unsigned short us8;

// ---------------------------------------------------------------------------
// K1: added[n] = (nn_m[nn_n[n]] != n); c_m histogram (added only, over nn_n);
//     ecnt[j] = #masters with nn_m=j  +  added[j]  (extended segment size).
__global__ void k_added_counts(const int* __restrict__ nn_n, const int* __restrict__ nn_m,
                               int* __restrict__ added, int* __restrict__ c_m,
                               int* __restrict__ ecnt) {
    int i = blockIdx.x * 256 + threadIdx.x;
    if (i < N_) {
        int m = nn_n[i];
        int a = (nn_m[m] != i) ? 1 : 0;
        added[i] = a;
        if (a) {
            atomicAdd(&c_m[m], 1);
            atomicAdd(&ecnt[i], 1);
        }
    }
    if (i < S_) {
        atomicAdd(&ecnt[nn_m[i]], 1);
    }
}

// ---------------------------------------------------------------------------
// K2: per-block sums of ecnt (1024 elements / block) for the exclusive scan.
__global__ void k_scan_blocksum(const int* __restrict__ ecnt, int* __restrict__ bsum) {
    __shared__ int sd[256];
    int b = blockIdx.x, t = threadIdx.x;
    int base = b * 1024 + t * 4;
    int s = 0;
#pragma unroll
    for (int k = 0; k < 4; k++) { int idx = base + k; if (idx < N_) s += ecnt[idx]; }
    sd[t] = s;
    __syncthreads();
    for (int off = 128; off > 0; off >>= 1) {
        if (t < off) sd[t] += sd[t + off];
        __syncthreads();
    }
    if (t == 0) bsum[b] = sd[0];
}

// K3: exclusive scan -> offs.
__global__ void k_scan_apply(const int* __restrict__ ecnt, const int* __restrict__ bsum,
                             int* __restrict__ offs) {
    __shared__ int sd[256];
    __shared__ int sp[256];
    int b = blockIdx.x, t = threadIdx.x;
    sp[t] = (t < b) ? bsum[t] : 0;
    __syncthreads();
    for (int off = 128; off > 0; off >>= 1) {
        if (t < off) sp[t] += sp[t + off];
        __syncthreads();
    }
    int prev = sp[0];

    int base = b * 1024 + t * 4;
    int v[4]; int s = 0;
#pragma unroll
    for (int k = 0; k < 4; k++) { int idx = base + k; v[k] = (idx < N_) ? ecnt[idx] : 0; s += v[k]; }
    sd[t] = s;
    __syncthreads();
    for (int off = 1; off < 256; off <<= 1) {
        int xv = (t >= off) ? sd[t - off] : 0;
        __syncthreads();
        sd[t] += xv;
        __syncthreads();
    }
    int run = prev + sd[t] - s;
#pragma unroll
    for (int k = 0; k < 4; k++) {
        int idx = base + k;
        if (idx < N_) offs[idx] = run;
        run += v[k];
    }
}

// K4: extended CSR fill — masters (nn_m inverse) plus the added contributor
//     nn_n[j] appended to segment j.
__global__ void k_fill(const int* __restrict__ nn_m, const int* __restrict__ nn_n,
                       const int* __restrict__ added, const int* __restrict__ offs,
                       int* __restrict__ fill, int* __restrict__ elist) {
    int i = blockIdx.x * 256 + threadIdx.x;
    if (i < S_) {
        int j = nn_m[i];
        int p = atomicAdd(&fill[j], 1);
        elist[offs[j] + p] = i;
    }
    if (i < N_ && added[i]) {
        int p = atomicAdd(&fill[i], 1);
        elist[offs[i] + p] = nn_n[i];
    }
}

// ---------------------------------------------------------------------------
// K5: We_n[j,:] = sum_{m in elist(j)} We_m[m,:] / (c_m[m]+1).
// One wave serves FOUR segments concurrently; lane = column l.
// Support loads (ecnt/offs/elist/c_m) are readfirstlane'd -> scalar s_load
// chain on the SMEM path; vector path carries only We_m row gathers.
// Epilogue: a block's 16 j's cover a DENSE 4 KB Wf sub-region -> stage hi/lo
// bf16 in a 4 KB LDS image, one barrier, one coalesced 16 B store per thread.
// Wf layout (ushort): [(ch*2+s)*4096 + ct*1024 + hl*512 + (l15+16*kq2)*8 + i]
//   for element (j,l): ch=j>>6, k=j&63, s=k>>5, kq2=(k>>3)&3, i=k&7,
//   ct=l>>4, l15=l&15.
__global__ __launch_bounds__(256) void k_wen(
        const float* __restrict__ We_m, const int* __restrict__ c_m,
        const int* __restrict__ ecnt, const int* __restrict__ offs,
        const int* __restrict__ elist, unsigned short* __restrict__ Wf) {
    __shared__ unsigned short sw[2048];       // 4 KB dense block image
    int t = threadIdx.x;
    int lane = t & 63;
    int wv = __builtin_amdgcn_readfirstlane(t >> 6);
    int jb = (blockIdx.x * 4 + wv) * 4;       // 4 segments per wave; always < N_
    int c[4], o[4];
    float acc[4];
#pragma unroll
    for (int s = 0; s < 4; s++) {
        int j = jb + s;
        c[s] = __builtin_amdgcn_readfirstlane(ecnt[j]);
        o[s] = __builtin_amdgcn_readfirstlane(offs[j]);
        acc[s] = 0.f;
    }
    int cmax = max(max(c[0], c[1]), max(c[2], c[3]));
    for (int q = 0; q < cmax; q++) {
        int mm[4];
#pragma unroll
        for (int s = 0; s < 4; s++)
            mm[s] = (q < c[s]) ? __builtin_amdgcn_readfirstlane(elist[o[s] + q]) : -1;
        float row[4], sc[4];
#pragma unroll
        for (int s = 0; s < 4; s++) {
            if (mm[s] >= 0) {
                row[s] = We_m[(size_t)mm[s] * 64 + lane]; // 4 independent row gathers
                sc[s]  = 1.0f / (float)(c_m[mm[s]] + 1);  // scalar load (uniform)
            }
        }
#pragma unroll
        for (int s = 0; s < 4; s++)
            if (mm[s] >= 0) acc[s] += row[s] * sc[s];
    }

    // ---- epilogue: hi/lo bf16 split -> LDS image -> dense cooperative store
    int ct  = lane >> 4;
    int l15 = lane & 15;
    int k0  = jb & 63;                 // wave-uniform; 4-aligned
    int i0  = k0 & 7;                  // 0 or 4
    int kq2p = (k0 >> 3) & 1;          // local half within block region
    int lbase = ct * 512 + (l15 + 16 * kq2p) * 8 + i0;   // hl=0 slot
    us4 hv, lv;
#pragma unroll
    for (int s2 = 0; s2 < 4; s2++) {
        float v = acc[s2];
        unsigned u = __float_as_uint(v);
        hv[s2] = (unsigned short)(u >> 16);
        float r = v - __uint_as_float(u & 0xffff0000u);
        lv[s2] = (unsigned short)(__float_as_uint(r) >> 16);
    }
    *(us4*)&sw[lbase]       = hv;
    *(us4*)&sw[lbase + 256] = lv;
    __syncthreads();
    int ch  = jb >> 6;                 // block-uniform
    int sH  = (k0 >> 5) & 1;           // block-uniform
    int kqb = (k0 >> 3) & 2;           // block-uniform
    size_t R = ((size_t)ch * 2 + sH) * 4096 + (size_t)kqb * 128;
    size_t g = R + (size_t)(t >> 6) * 1024 + (size_t)((t >> 5) & 1) * 512
                 + (size_t)(t & 31) * 8;
    *(us8*)(Wf + g) = *(const us8*)&sw[t * 8];   // 16 B coalesced
}

// ---------------------------------------------------------------------------
// K6: encode GEMM z[b,l] = sum_n x[b,n]*We_n[n,l]  via MFMA.
// fp32 emulated with bf16 hi/lo split: a*b ~= ah*bh + al*bh + ah*bl.
// No LDS, no barriers. Wave wv owns rows [16wv,16wv+16) (disjoint A bands);
// A fragments load straight from x in native MFMA layout. B fragments come
// pre-split/pre-swizzled from Wf (linear lane*16B loads); shared via L1/L2.
// Epilogue: dense atomicAdd into zp2[row][b*64+l].
__global__ __launch_bounds__(256) void k_encode(const float* __restrict__ x,
        const unsigned short* __restrict__ Wf, float* __restrict__ zp2) {
    int t = threadIdx.x;
    int lane = t & 63;
    int wv = t >> 6;                 // row band
    int mrow = lane & 15;            // A row within band / C col
    int kq = lane >> 4;              // A k-quad / C row-quad
    const float* xbase = x + (size_t)(wv * 16 + mrow) * N_ + kq * 8;
    f32x4 acc[4];
#pragma unroll
    for (int ct = 0; ct < 4; ct++) acc[ct] = (f32x4){0.f, 0.f, 0.f, 0.f};

    for (int cc = 0; cc < 4; cc++) {
        int c = blockIdx.x * 4 + cc;
        if (c >= NCHUNK) break;
        int n0 = c * 64;
#pragma unroll
        for (int s = 0; s < 2; s++) {
            // ---- A raw load (8 consecutive fp32 along k), tail-guarded ----
            float av[8];
            if (n0 + s * 32 + kq * 8 + 8 <= N_) {
                float4 a0 = *(const float4*)(xbase + n0 + s * 32);
                float4 a1 = *(const float4*)(xbase + n0 + s * 32 + 4);
                av[0] = a0.x; av[1] = a0.y; av[2] = a0.z; av[3] = a0.w;
                av[4] = a1.x; av[5] = a1.y; av[6] = a1.z; av[7] = a1.w;
            } else {
#pragma unroll
                for (int i = 0; i < 8; i++) av[i] = 0.f;
            }
            // ---- B fragments: linear, coalesced, already bf16 hi/lo ----
            const bf16x8* bp = (const bf16x8*)Wf + ((size_t)c * 2 + s) * 512 + lane;
            bf16x8 bh[4], bl[4];
#pragma unroll
            for (int ct = 0; ct < 4; ct++) {
                bh[ct] = bp[ct * 128];
                bl[ct] = bp[ct * 128 + 64];
            }
            // ---- split A into hi/lo bf16 ----
            bf16x8 ah, al;
#pragma unroll
            for (int i = 0; i < 8; i++) {
                float v = av[i];
                unsigned u = __float_as_uint(v);
                ah[i] = (short)(u >> 16);
                float r = v - __uint_as_float(u & 0xffff0000u);
                al[i] = (short)(__float_as_uint(r) >> 16);
            }
            // ---- 12 MFMAs: 4 col-tiles x 3 split terms ----
#pragma unroll
            for (int ct = 0; ct < 4; ct++) {
                acc[ct] = __builtin_amdgcn_mfma_f32_16x16x32_bf16(ah, bh[ct], acc[ct], 0, 0, 0);
                acc[ct] = __builtin_amdgcn_mfma_f32_16x16x32_bf16(al, bh[ct], acc[ct], 0, 0, 0);
                acc[ct] = __builtin_amdgcn_mfma_f32_16x16x32_bf16(ah, bl[ct], acc[ct], 0, 0, 0);
            }
        }
    }

    // Epilogue: C/D layout col=lane&15, row=(lane>>4)*4+reg (verified m89).
    int row = blockIdx.x & 63;
    float* zr = zp2 + row * 4096;
#pragma unroll
    for (int ct = 0; ct < 4; ct++) {
#pragma unroll
        for (int r = 0; r < 4; r++) {
            int b = wv * 16 + kq * 4 + r;
            int l = ct * 16 + mrow;
            atomicAdd(&zr[b * 64 + l], acc[ct][r]);   // 16 consecutive floats/quad
        }
    }
}

// K7: z2g[l*64+b] = sum_rows zp2[b*64+l] + be[l].  (zp2 is b-major)
__global__ void k_zred(const float* __restrict__ zp2, const float* __restrict__ be_m,
                       float* __restrict__ z2g) {
    int slot = blockIdx.x * 256 + threadIdx.x;   // 16 blocks x 256, slot = b*64+l
    float s = 0.f;
    for (int r = 0; r < 64; r++) s += zp2[r * 4096 + slot];
    int b = slot >> 6, l = slot & 63;
    z2g[l * 64 + b] = s + be_m[l];
}

// ---------------------------------------------------------------------------
// K8: P[m,b] = sum_l z2g[l*64+b] * Wd_m[l,m] + bd_m[m].  P layout [S][64].
// RESTRUCTURED so the live accumulator is acc[16] (v4's acc[64] was spilled
// to scratch by the allocator: VGPR_Count=36 with 64 live floats -> 8x slow).
// Block = 64-m tile; wave bg = t>>6 owns b in [bg*16, bg*16+16); lane = m.
// Wd tile (64x64, 16 KB) staged in LDS (coalesced float4); inner read
// ws[l*64+m] is 64-consecutive -> 2-way bank alias (free). z2g slice is
// wave-uniform -> s_load_dwordx16 per l, pipelined via unroll.
__global__ __launch_bounds__(256) void k_pmat(
        const float* __restrict__ Wd_m, const float* __restrict__ bd_m,
        const float* __restrict__ z2g, float* __restrict__ P) {
    __shared__ float ws[64 * 64];
    int t = threadIdx.x;
    int m0 = blockIdx.x * 64;
    // stage Wd_m[l][m0:m0+64] tile: 4 float4 loads per thread, coalesced
#pragma unroll
    for (int r = 0; r < 4; r++) {
        int flat = r * 256 + t;          // 0..1023
        int l = flat >> 4;               // 0..63
        int c4 = flat & 15;              // 0..15
        float4 v = *(const float4*)&Wd_m[(size_t)l * S_ + m0 + c4 * 4];
        *(float4*)&ws[l * 64 + c4 * 4] = v;
    }
    __syncthreads();

    int m = t & 63;
    int bg = __builtin_amdgcn_readfirstlane(t >> 6);   // wave-uniform b-group
    float bd = bd_m[m0 + m];
    float acc[16];
#pragma unroll
    for (int q = 0; q < 16; q++) acc[q] = bd;
    const float* zb = z2g + bg * 16;
#pragma unroll 4
    for (int l = 0; l < 64; l++) {
        float w = ws[l * 64 + m];
        const float* zr = zb + l * 64;   // wave-uniform -> s_load_dwordx16
#pragma unroll
        for (int q = 0; q < 16; q++) acc[q] += w * zr[q];
    }

    float4* Pv = (float4*)&P[(size_t)(m0 + m) * 64 + bg * 16];
#pragma unroll
    for (int q4 = 0; q4 < 4; q4++)
        Pv[q4] = make_float4(acc[q4 * 4 + 0], acc[q4 * 4 + 1],
                             acc[q4 * 4 + 2], acc[q4 * 4 + 3]);
}

// ---------------------------------------------------------------------------
// K9: out[b,j] = (sum_{m in elist(j)} P[m,b]) / max(ecnt[j],1).
// Wave serves its 16 jj's in 4 groups of 4 concurrent segments.
// Support loads readfirstlane'd (scalar chain); lane = b; 64-j tile through
// LDS for coalesced out writes.
__global__ __launch_bounds__(256) void k_decode(const float* __restrict__ P,
        const int* __restrict__ ecnt, const int* __restrict__ offs,
        const int* __restrict__ elist, float* __restrict__ out) {
    __shared__ float tile[64][65];
    int t = threadIdx.x;
    int wv = __builtin_amdgcn_readfirstlane(t >> 6);
    int lane = t & 63;
    int j0 = blockIdx.x * 64;
    for (int g = 0; g < 4; g++) {
        int jjb = wv * 16 + g * 4;
        int c[4], o[4];
        float acc[4];
#pragma unroll
        for (int s = 0; s < 4; s++) {
            int j = j0 + jjb + s;
            bool v = (j < N_);
            c[s] = v ? __builtin_amdgcn_readfirstlane(ecnt[j]) : 0;
            o[s] = v ? __builtin_amdgcn_readfirstlane(offs[j]) : 0;
            acc[s] = 0.f;
        }
        int cmax = max(max(c[0], c[1]), max(c[2], c[3]));
        for (int q = 0; q < cmax; q++) {
            int mm[4];
#pragma unroll
            for (int s = 0; s < 4; s++)
                mm[s] = (q < c[s]) ? __builtin_amdgcn_readfirstlane(elist[o[s] + q]) : -1;
#pragma unroll
            for (int s = 0; s < 4; s++)
                if (mm[s] >= 0) acc[s] += P[(size_t)mm[s] * 64 + lane]; // 4 row gathers in flight
        }
#pragma unroll
        for (int s = 0; s < 4; s++) {
            int cc = (c[s] > 1) ? c[s] : 1;
            tile[jjb + s][lane] = acc[s] * (1.0f / (float)cc);
        }
    }
    __syncthreads();
#pragma unroll
    for (int r = 0; r < 16; r++) {
        int b = r * 4 + wv;
        int j = j0 + lane;
        if (j < N_) out[(size_t)b * N_ + j] = tile[lane][b];
    }
}

// ---------------------------------------------------------------------------
extern "C" void kernel_launch(void* const* d_in, const int* in_sizes, int n_in,
                              void* d_out, int out_size, void* d_ws, size_t ws_size,
                              hipStream_t stream) {
    const float* We_m = (const float*)d_in[0];
    const float* be_m = (const float*)d_in[1];
    const float* Wd_m = (const float*)d_in[2];
    const float* bd_m = (const float*)d_in[3];
    const float* x    = (const float*)d_in[4];
    const int*   nn_n = (const int*)d_in[5];
    const int*   nn_m = (const int*)d_in[6];
    float* out = (float*)d_out;
    char* ws = (char*)d_ws;

    // Workspace layout (byte offsets). Region 0 holds Wf (pre-split bf16
    // We_n fragments, 3907*16384 = 64,012,288 B) during the encode phase,
    // then is reused for P [S,64] (51.2 MB) in the decode phase.
    unsigned short* Wf = (unsigned short*)(ws + 0);
    float* P     = (float*)(ws + 0);           // aliases Wf; phase-ordered
    int*   c_m   = (int*)(ws + 64012288);      //    800,000 B (zeroed)
    int*   ecnt  = (int*)(ws + 64812288);      //  1,000,000 B (zeroed)
    int*   fill  = (int*)(ws + 65812288);      //  1,000,000 B (zeroed)
    int*   added = (int*)(ws + 66812288);      //  1,000,000 B
    int*   offs  = (int*)(ws + 67812288);      //  1,000,000 B
    int*   elist = (int*)(ws + 68812288);      //  2,000,000 B (<= (S+N)*4 = 1.8 MB)
    float* zp2   = (float*)(ws + 70812288);    //  1,048,576 B (64 x 4096, zeroed)
    float* z2g   = (float*)(ws + 71860864);    //     16,384 B
    int*   bsum  = (int*)(ws + 71877248);      //      1,024 B
    // total ~71.9 MB

    hipMemsetAsync(ws + 64012288, 0, 2800000, stream);       // c_m, ecnt, fill
    hipMemsetAsync(zp2, 0, 1048576, stream);                 // zp2
    hipMemsetAsync(ws + (size_t)3906 * 16384, 0, 16384, stream); // Wf tail chunk pad

    k_added_counts<<<977, 256, 0, stream>>>(nn_n, nn_m, added, c_m, ecnt);
    k_scan_blocksum<<<245, 256, 0, stream>>>(ecnt, bsum);
    k_scan_apply<<<245, 256, 0, stream>>>(ecnt, bsum, offs);
    k_fill<<<977, 256, 0, stream>>>(nn_m, nn_n, added, offs, fill, elist);
    k_wen<<<15625, 256, 0, stream>>>(We_m, c_m, ecnt, offs, elist, Wf);
    k_encode<<<ENC_BLOCKS, 256, 0, stream>>>(x, Wf, zp2);
    k_zred<<<16, 256, 0, stream>>>(zp2, be_m, z2g);
    k_pmat<<<3125, 256, 0, stream>>>(Wd_m, bd_m, z2g, P);
    k_decode<<<3907, 256, 0, stream>>>(P, ecnt, offs, elist, out);
}

// Round 5
// 358.566 us; speedup vs baseline: 1.4590x; 1.0218x over previous
//
#include <hip/hip_runtime.h>

// Problem constants (match reference)
constexpr int S_ = 200000;   // master nodes
constexpr int N_ = 250000;   // new nodes
// L = B = 64

constexpr int NCHUNK = (N_ + 63) / 64;   // 3907
constexpr int ENC_BLOCKS = (NCHUNK + 3) / 4;  // 977, 4 chunks per block

typedef __attribute__((ext_vector_type(8))) short bf16x8;
typedef __attribute__((ext_vector_type(4))) float f32x4;
typedef __attribute__((ext_vector_type(4))) unsigned short us4;
typedef __attribute__((ext_vector_type(8))) unsigned short us8;

// ---------------------------------------------------------------------------
// K1: added[n] = (nn_m[nn_n[n]] != n); c_m histogram (added only, over nn_n);
//     ecnt[j] = #masters with nn_m=j  +  added[j]  (extended segment size).
__global__ void k_added_counts(const int* __restrict__ nn_n, const int* __restrict__ nn_m,
                               int* __restrict__ added, int* __restrict__ c_m,
                               int* __restrict__ ecnt) {
    int i = blockIdx.x * 256 + threadIdx.x;
    if (i < N_) {
        int m = nn_n[i];
        int a = (nn_m[m] != i) ? 1 : 0;
        added[i] = a;
        if (a) {
            atomicAdd(&c_m[m], 1);
            atomicAdd(&ecnt[i], 1);
        }
    }
    if (i < S_) {
        atomicAdd(&ecnt[nn_m[i]], 1);
    }
}

// ---------------------------------------------------------------------------
// K2: per-block sums of ecnt (1024 elements / block) for the exclusive scan.
__global__ void k_scan_blocksum(const int* __restrict__ ecnt, int* __restrict__ bsum) {
    __shared__ int sd[256];
    int b = blockIdx.x, t = threadIdx.x;
    int base = b * 1024 + t * 4;
    int s = 0;
#pragma unroll
    for (int k = 0; k < 4; k++) { int idx = base + k; if (idx < N_) s += ecnt[idx]; }
    sd[t] = s;
    __syncthreads();
    for (int off = 128; off > 0; off >>= 1) {
        if (t < off) sd[t] += sd[t + off];
        __syncthreads();
    }
    if (t == 0) bsum[b] = sd[0];
}

// K3: exclusive scan -> offs.
__global__ void k_scan_apply(const int* __restrict__ ecnt, const int* __restrict__ bsum,
                             int* __restrict__ offs) {
    __shared__ int sd[256];
    __shared__ int sp[256];
    int b = blockIdx.x, t = threadIdx.x;
    sp[t] = (t < b) ? bsum[t] : 0;
    __syncthreads();
    for (int off = 128; off > 0; off >>= 1) {
        if (t < off) sp[t] += sp[t + off];
        __syncthreads();
    }
    int prev = sp[0];

    int base = b * 1024 + t * 4;
    int v[4]; int s = 0;
#pragma unroll
    for (int k = 0; k < 4; k++) { int idx = base + k; v[k] = (idx < N_) ? ecnt[idx] : 0; s += v[k]; }
    sd[t] = s;
    __syncthreads();
    for (int off = 1; off < 256; off <<= 1) {
        int xv = (t >= off) ? sd[t - off] : 0;
        __syncthreads();
        sd[t] += xv;
        __syncthreads();
    }
    int run = prev + sd[t] - s;
#pragma unroll
    for (int k = 0; k < 4; k++) {
        int idx = base + k;
        if (idx < N_) offs[idx] = run;
        run += v[k];
    }
}

// K4: extended CSR fill — masters (nn_m inverse) plus the added contributor
//     nn_n[j] appended to segment j.
__global__ void k_fill(const int* __restrict__ nn_m, const int* __restrict__ nn_n,
                       const int* __restrict__ added, const int* __restrict__ offs,
                       int* __restrict__ fill, int* __restrict__ elist) {
    int i = blockIdx.x * 256 + threadIdx.x;
    if (i < S_) {
        int j = nn_m[i];
        int p = atomicAdd(&fill[j], 1);
        elist[offs[j] + p] = i;
    }
    if (i < N_ && added[i]) {
        int p = atomicAdd(&fill[i], 1);
        elist[offs[i] + p] = nn_n[i];
    }
}

// ---------------------------------------------------------------------------
// K5: We_n[j,:] = sum_{m in elist(j)} We_m[m,:] / (c_m[m]+1).
// One wave serves SIXTEEN segments concurrently (16 independent 256-B row
// gathers in flight per latency round); block = one full 64-j chunk.
// Support loads (ecnt/offs/elist/c_m) readfirstlane'd -> scalar SMEM chain.
// Epilogue: block covers exactly one 16 KB Wf chunk. Per-thread hi/lo values
// for s=0..7 / 8..15 are CONTIGUOUS 16-B runs in the fragment layout
// (i = s&7; kq2 wave-uniform) -> 4 conflict-free ds_write_b128 + dense
// cooperative 16-B global stores. Covers OOB-j positions with zeros.
// Wf layout (ushort): [(ch*2+sH)*4096 + ct*1024 + hl*512 + (l15+16*kq2)*8 + i]
//   for element (j,l): ch=j>>6, k=j&63, sH=k>>5, kq2=(k>>3)&3, i=k&7,
//   ct=l>>4, l15=l&15.
__global__ __launch_bounds__(256) void k_wen(
        const float* __restrict__ We_m, const int* __restrict__ c_m,
        const int* __restrict__ ecnt, const int* __restrict__ offs,
        const int* __restrict__ elist, unsigned short* __restrict__ Wf) {
    __shared__ unsigned short sw[8192];       // 16 KB chunk image
    int t = threadIdx.x;
    int lane = t & 63;
    int wv = __builtin_amdgcn_readfirstlane(t >> 6);
    int ch = blockIdx.x;
    int jb = ch * 64 + wv * 16;               // 16 segments per wave
    int c[16], o[16];
    float acc[16];
#pragma unroll
    for (int s = 0; s < 16; s++) {
        int j = jb + s;
        bool v = (j < N_);
        c[s] = v ? __builtin_amdgcn_readfirstlane(ecnt[j]) : 0;
        o[s] = v ? __builtin_amdgcn_readfirstlane(offs[j]) : 0;
        acc[s] = 0.f;
    }
    int cmax = 0;
#pragma unroll
    for (int s = 0; s < 16; s++) cmax = max(cmax, c[s]);
    for (int q = 0; q < cmax; q++) {
        int mm[16];
#pragma unroll
        for (int s = 0; s < 16; s++)
            mm[s] = (q < c[s]) ? __builtin_amdgcn_readfirstlane(elist[o[s] + q]) : -1;
        float row[16], sc[16];
#pragma unroll
        for (int s = 0; s < 16; s++) {
            if (mm[s] >= 0) {
                row[s] = We_m[(size_t)mm[s] * 64 + lane];   // 16 gathers in flight
                sc[s]  = 1.0f / (float)(c_m[mm[s]] + 1);    // scalar load (uniform)
            }
        }
#pragma unroll
        for (int s = 0; s < 16; s++)
            if (mm[s] >= 0) acc[s] += row[s] * sc[s];
    }

    // ---- epilogue: hi/lo bf16 split -> contiguous us8 runs -> LDS -> global
    int ct = lane >> 4, l15 = lane & 15;
    int k0 = wv * 16;                  // wave-uniform
    int sH = k0 >> 5;                  // 0,0,1,1 for wv 0..3
    int kq20 = (k0 >> 3) & 3;          // 0,2,0,2 for wv 0..3
    us8 h0, h1, l0, l1;
#pragma unroll
    for (int s = 0; s < 8; s++) {
        float v = acc[s];
        unsigned u = __float_as_uint(v);
        h0[s] = (unsigned short)(u >> 16);
        float r = v - __uint_as_float(u & 0xffff0000u);
        l0[s] = (unsigned short)(__float_as_uint(r) >> 16);
        float v1 = acc[8 + s];
        unsigned u1 = __float_as_uint(v1);
        h1[s] = (unsigned short)(u1 >> 16);
        float r1 = v1 - __uint_as_float(u1 & 0xffff0000u);
        l1[s] = (unsigned short)(__float_as_uint(r1) >> 16);
    }
    int base0 = sH * 4096 + ct * 1024 + (l15 + 16 * kq20) * 8;  // s=0..7 (hi)
    int base1 = base0 + 128;                                    // s=8..15 (kq2+1)
    *(us8*)&sw[base0]       = h0;
    *(us8*)&sw[base0 + 512] = l0;
    *(us8*)&sw[base1]       = h1;
    *(us8*)&sw[base1 + 512] = l1;
    __syncthreads();
    size_t R = (size_t)ch * 8192;
#pragma unroll
    for (int r = 0; r < 4; r++) {
        int idx = r * 2048 + t * 8;
        *(us8*)(Wf + R + idx) = *(const us8*)&sw[idx];   // 16 B coalesced
    }
}

// ---------------------------------------------------------------------------
// K6: encode GEMM z[b,l] = sum_n x[b,n]*We_n[n,l]  via MFMA.
// fp32 emulated with bf16 hi/lo split: a*b ~= ah*bh + al*bh + ah*bl.
// No LDS, no barriers. Wave wv owns rows [16wv,16wv+16) (disjoint A bands);
// A fragments load straight from x in native MFMA layout. B fragments come
// pre-split/pre-swizzled from Wf (linear lane*16B loads); shared via L1/L2.
// Epilogue: dense atomicAdd into zp2[row][b*64+l].
__global__ __launch_bounds__(256) void k_encode(const float* __restrict__ x,
        const unsigned short* __restrict__ Wf, float* __restrict__ zp2) {
    int t = threadIdx.x;
    int lane = t & 63;
    int wv = t >> 6;                 // row band
    int mrow = lane & 15;            // A row within band / C col
    int kq = lane >> 4;              // A k-quad / C row-quad
    const float* xbase = x + (size_t)(wv * 16 + mrow) * N_ + kq * 8;
    f32x4 acc[4];
#pragma unroll
    for (int ct = 0; ct < 4; ct++) acc[ct] = (f32x4){0.f, 0.f, 0.f, 0.f};

    for (int cc = 0; cc < 4; cc++) {
        int c = blockIdx.x * 4 + cc;
        if (c >= NCHUNK) break;
        int n0 = c * 64;
#pragma unroll
        for (int s = 0; s < 2; s++) {
            // ---- A raw load (8 consecutive fp32 along k), tail-guarded ----
            float av[8];
            if (n0 + s * 32 + kq * 8 + 8 <= N_) {
                float4 a0 = *(const float4*)(xbase + n0 + s * 32);
                float4 a1 = *(const float4*)(xbase + n0 + s * 32 + 4);
                av[0] = a0.x; av[1] = a0.y; av[2] = a0.z; av[3] = a0.w;
                av[4] = a1.x; av[5] = a1.y; av[6] = a1.z; av[7] = a1.w;
            } else {
#pragma unroll
                for (int i = 0; i < 8; i++) av[i] = 0.f;
            }
            // ---- B fragments: linear, coalesced, already bf16 hi/lo ----
            const bf16x8* bp = (const bf16x8*)Wf + ((size_t)c * 2 + s) * 512 + lane;
            bf16x8 bh[4], bl[4];
#pragma unroll
            for (int ct = 0; ct < 4; ct++) {
                bh[ct] = bp[ct * 128];
                bl[ct] = bp[ct * 128 + 64];
            }
            // ---- split A into hi/lo bf16 ----
            bf16x8 ah, al;
#pragma unroll
            for (int i = 0; i < 8; i++) {
                float v = av[i];
                unsigned u = __float_as_uint(v);
                ah[i] = (short)(u >> 16);
                float r = v - __uint_as_float(u & 0xffff0000u);
                al[i] = (short)(__float_as_uint(r) >> 16);
            }
            // ---- 12 MFMAs: 4 col-tiles x 3 split terms ----
#pragma unroll
            for (int ct = 0; ct < 4; ct++) {
                acc[ct] = __builtin_amdgcn_mfma_f32_16x16x32_bf16(ah, bh[ct], acc[ct], 0, 0, 0);
                acc[ct] = __builtin_amdgcn_mfma_f32_16x16x32_bf16(al, bh[ct], acc[ct], 0, 0, 0);
                acc[ct] = __builtin_amdgcn_mfma_f32_16x16x32_bf16(ah, bl[ct], acc[ct], 0, 0, 0);
            }
        }
    }

    // Epilogue: C/D layout col=lane&15, row=(lane>>4)*4+reg (verified m89).
    int row = blockIdx.x & 63;
    float* zr = zp2 + row * 4096;
#pragma unroll
    for (int ct = 0; ct < 4; ct++) {
#pragma unroll
        for (int r = 0; r < 4; r++) {
            int b = wv * 16 + kq * 4 + r;
            int l = ct * 16 + mrow;
            atomicAdd(&zr[b * 64 + l], acc[ct][r]);   // 16 consecutive floats/quad
        }
    }
}

// K7: z2g[l*64+b] = sum_rows zp2[b*64+l] + be[l].  (zp2 is b-major)
__global__ void k_zred(const float* __restrict__ zp2, const float* __restrict__ be_m,
                       float* __restrict__ z2g) {
    int slot = blockIdx.x * 256 + threadIdx.x;   // 16 blocks x 256, slot = b*64+l
    float s = 0.f;
    for (int r = 0; r < 64; r++) s += zp2[r * 4096 + slot];
    int b = slot >> 6, l = slot & 63;
    z2g[l * 64 + b] = s + be_m[l];
}

// ---------------------------------------------------------------------------
// K8: P[m,b] = sum_l z2g[l*64+b] * Wd_m[l,m] + bd_m[m].  P layout [S][64].
// Live accumulator is acc[16]. Block = 64-m tile; wave bg owns b in
// [bg*16, bg*16+16); lane = m. Wd tile staged in LDS (coalesced float4);
// inner read ws[l*64+m] 64-consecutive -> 2-way alias (free). z2g slice
// wave-uniform -> s_load_dwordx16 per l, pipelined via unroll.
__global__ __launch_bounds__(256) void k_pmat(
        const float* __restrict__ Wd_m, const float* __restrict__ bd_m,
        const float* __restrict__ z2g, float* __restrict__ P) {
    __shared__ float ws[64 * 64];
    int t = threadIdx.x;
    int m0 = blockIdx.x * 64;
    // stage Wd_m[l][m0:m0+64] tile: 4 float4 loads per thread, coalesced
#pragma unroll
    for (int r = 0; r < 4; r++) {
        int flat = r * 256 + t;          // 0..1023
        int l = flat >> 4;               // 0..63
        int c4 = flat & 15;              // 0..15
        float4 v = *(const float4*)&Wd_m[(size_t)l * S_ + m0 + c4 * 4];
        *(float4*)&ws[l * 64 + c4 * 4] = v;
    }
    __syncthreads();

    int m = t & 63;
    int bg = __builtin_amdgcn_readfirstlane(t >> 6);   // wave-uniform b-group
    float bd = bd_m[m0 + m];
    float acc[16];
#pragma unroll
    for (int q = 0; q < 16; q++) acc[q] = bd;
    const float* zb = z2g + bg * 16;
#pragma unroll 4
    for (int l = 0; l < 64; l++) {
        float w = ws[l * 64 + m];
        const float* zr = zb + l * 64;   // wave-uniform -> s_load_dwordx16
#pragma unroll
        for (int q = 0; q < 16; q++) acc[q] += w * zr[q];
    }

    float4* Pv = (float4*)&P[(size_t)(m0 + m) * 64 + bg * 16];
#pragma unroll
    for (int q4 = 0; q4 < 4; q4++)
        Pv[q4] = make_float4(acc[q4 * 4 + 0], acc[q4 * 4 + 1],
                             acc[q4 * 4 + 2], acc[q4 * 4 + 3]);
}

// ---------------------------------------------------------------------------
// K9: out[b,j] = (sum_{m in elist(j)} P[m,b]) / max(ecnt[j],1).
// One wave serves SIXTEEN segments concurrently (16 row gathers in flight
// per latency round, was 4 in 4 serial groups). Support loads scalar.
// lane = b; 64-j tile through LDS for coalesced out writes.
__global__ __launch_bounds__(256) void k_decode(const float* __restrict__ P,
        const int* __restrict__ ecnt, const int* __restrict__ offs,
        const int* __restrict__ elist, float* __restrict__ out) {
    __shared__ float tile[64][65];
    int t = threadIdx.x;
    int wv = __builtin_amdgcn_readfirstlane(t >> 6);
    int lane = t & 63;
    int j0 = blockIdx.x * 64;
    int jb = j0 + wv * 16;
    int c[16], o[16];
    float acc[16];
#pragma unroll
    for (int s = 0; s < 16; s++) {
        int j = jb + s;
        bool v = (j < N_);
        c[s] = v ? __builtin_amdgcn_readfirstlane(ecnt[j]) : 0;
        o[s] = v ? __builtin_amdgcn_readfirstlane(offs[j]) : 0;
        acc[s] = 0.f;
    }
    int cmax = 0;
#pragma unroll
    for (int s = 0; s < 16; s++) cmax = max(cmax, c[s]);
    for (int q = 0; q < cmax; q++) {
        int mm[16];
#pragma unroll
        for (int s = 0; s < 16; s++)
            mm[s] = (q < c[s]) ? __builtin_amdgcn_readfirstlane(elist[o[s] + q]) : -1;
        float row[16];
#pragma unroll
        for (int s = 0; s < 16; s++)
            if (mm[s] >= 0) row[s] = P[(size_t)mm[s] * 64 + lane];  // 16 in flight
#pragma unroll
        for (int s = 0; s < 16; s++)
            if (mm[s] >= 0) acc[s] += row[s];
    }
#pragma unroll
    for (int s = 0; s < 16; s++) {
        int cc = (c[s] > 1) ? c[s] : 1;
        tile[wv * 16 + s][lane] = acc[s] * (1.0f / (float)cc);
    }
    __syncthreads();
#pragma unroll
    for (int r = 0; r < 16; r++) {
        int b = r * 4 + wv;
        int j = j0 + lane;
        if (j < N_) out[(size_t)b * N_ + j] = tile[lane][b];
    }
}

// ---------------------------------------------------------------------------
extern "C" void kernel_launch(void* const* d_in, const int* in_sizes, int n_in,
                              void* d_out, int out_size, void* d_ws, size_t ws_size,
                              hipStream_t stream) {
    const float* We_m = (const float*)d_in[0];
    const float* be_m = (const float*)d_in[1];
    const float* Wd_m = (const float*)d_in[2];
    const float* bd_m = (const float*)d_in[3];
    const float* x    = (const float*)d_in[4];
    const int*   nn_n = (const int*)d_in[5];
    const int*   nn_m = (const int*)d_in[6];
    float* out = (float*)d_out;
    char* ws = (char*)d_ws;

    // Workspace layout (byte offsets). Region 0 holds Wf (pre-split bf16
    // We_n fragments, 3907*16384 = 64,012,288 B) during the encode phase,
    // then is reused for P [S,64] (51.2 MB) in the decode phase.
    unsigned short* Wf = (unsigned short*)(ws + 0);
    float* P     = (float*)(ws + 0);           // aliases Wf; phase-ordered
    int*   c_m   = (int*)(ws + 64012288);      //    800,000 B (zeroed)
    int*   ecnt  = (int*)(ws + 64812288);      //  1,000,000 B (zeroed)
    int*   fill  = (int*)(ws + 65812288);      //  1,000,000 B (zeroed)
    int*   added = (int*)(ws + 66812288);      //  1,000,000 B
    int*   offs  = (int*)(ws + 67812288);      //  1,000,000 B
    int*   elist = (int*)(ws + 68812288);      //  2,000,000 B (<= (S+N)*4 = 1.8 MB)
    float* zp2   = (float*)(ws + 70812288);    //  1,048,576 B (64 x 4096, zeroed)
    float* z2g   = (float*)(ws + 71860864);    //     16,384 B
    int*   bsum  = (int*)(ws + 71877248);      //      1,024 B
    // total ~71.9 MB

    hipMemsetAsync(ws + 64012288, 0, 2800000, stream);       // c_m, ecnt, fill
    hipMemsetAsync(zp2, 0, 1048576, stream);                 // zp2

    k_added_counts<<<977, 256, 0, stream>>>(nn_n, nn_m, added, c_m, ecnt);
    k_scan_blocksum<<<245, 256, 0, stream>>>(ecnt, bsum);
    k_scan_apply<<<245, 256, 0, stream>>>(ecnt, bsum, offs);
    k_fill<<<977, 256, 0, stream>>>(nn_m, nn_n, added, offs, fill, elist);
    k_wen<<<NCHUNK, 256, 0, stream>>>(We_m, c_m, ecnt, offs, elist, Wf);
    k_encode<<<ENC_BLOCKS, 256, 0, stream>>>(x, Wf, zp2);
    k_zred<<<16, 256, 0, stream>>>(zp2, be_m, z2g);
    k_pmat<<<3125, 256, 0, stream>>>(Wd_m, bd_m, z2g, P);
    k_decode<<<3907, 256, 0, stream>>>(P, ecnt, offs, elist, out);
}